// Round 22
// baseline (211.290 us; speedup 1.0000x reference)
//
#include <hip/hip_runtime.h>

// ModernBertAttention fused pipeline, bf16 MFMA, fp32 I/O.
// B=4 S=2048 H=1024 NH=16 D=64.

typedef __bf16 bf16x8 __attribute__((ext_vector_type(8)));
typedef float f32x4 __attribute__((ext_vector_type(4)));
typedef float f32x16 __attribute__((ext_vector_type(16)));
typedef unsigned short u16x8 __attribute__((ext_vector_type(8)));
typedef unsigned short u16x4 __attribute__((ext_vector_type(4)));
typedef const __attribute__((address_space(1))) void* gptr_t;
typedef __attribute__((address_space(3))) void* lptr_t;

template <int N> struct ic { static constexpr int v = N; };
struct pu4 { unsigned u[4]; };

__device__ __forceinline__ unsigned short f2bf(float f) {
  union { float f; unsigned u; } v; v.f = f;
  unsigned r = (v.u + 0x7fffu + ((v.u >> 16) & 1u)) >> 16;  // RNE
  return (unsigned short)r;
}

__device__ __forceinline__ unsigned short f2bfn(float f) {
  union { __bf16 h; unsigned short u; } v;
  v.h = (__bf16)f;  // native v_cvt
  return v.u;
}

__device__ __forceinline__ unsigned cvtpk(float lo, float hi_) {
  unsigned r;
  asm("v_cvt_pk_bf16_f32 %0, %1, %2" : "=v"(r) : "v"(lo), "v"(hi_));
  return r;
}

__device__ __forceinline__ void gld16(const void* g, void* l) {
  __builtin_amdgcn_global_load_lds((gptr_t)g, (lptr_t)l, 16, 0, 0);
}

// fused f32->bf16 for hidden (8M elems) + 4 weights (4x1M elems, contiguous dst)
__global__ __launch_bounds__(256) void cvt_all(
    const float* __restrict__ hidden, const float* __restrict__ Wq,
    const float* __restrict__ Wk, const float* __restrict__ Wv,
    const float* __restrict__ Wo, unsigned short* __restrict__ Xb,
    unsigned short* __restrict__ Wb) {
  size_t i8 = ((size_t)blockIdx.x * 256 + threadIdx.x) * 8;
  const float* src;
  unsigned short* dst;
  if (i8 < 8388608) {
    src = hidden + i8;
    dst = Xb + i8;
  } else {
    size_t r = i8 - 8388608;
    int wsel = (int)(r >> 20);
    size_t off = r & 1048575;
    const float* wsrc = (wsel == 0) ? Wq : (wsel == 1) ? Wk : (wsel == 2) ? Wv : Wo;
    src = wsrc + off;
    dst = Wb + r;
  }
  f32x4 a = *(const f32x4*)(src);
  f32x4 b = *(const f32x4*)(src + 4);
  u16x8 o;
  o[0] = f2bf(a[0]); o[1] = f2bf(a[1]); o[2] = f2bf(a[2]); o[3] = f2bf(a[3]);
  o[4] = f2bf(b[0]); o[5] = f2bf(b[1]); o[6] = f2bf(b[2]); o[7] = f2bf(b[3]);
  *(u16x8*)dst = o;
}

// Fused QKV GEMM v2: 128x128 C-tile for all three weights; 12 waves;
// double-buffered LDS + counted-vmcnt pipeline + XCD swizzle. (Unchanged.)
__global__ __launch_bounds__(768, 3) void gemm_qkv(
    const unsigned short* __restrict__ A,
    const unsigned short* __restrict__ W0, const unsigned short* __restrict__ W1,
    const unsigned short* __restrict__ W2,
    const float* __restrict__ cosT, const float* __restrict__ sinT,
    unsigned short* __restrict__ Qh, unsigned short* __restrict__ Kh,
    unsigned short* __restrict__ Vh) {
  __shared__ char sm[131072];  // 2 x (A | W0 | W1 | W2), 16KB each
  const int tid = threadIdx.x, lane = tid & 63, w = tid >> 6;
  const int l15 = lane & 15, h2 = lane >> 4;
  const int z = w >> 2, sub = w & 3;
  const int wm = sub >> 1, wn = sub & 1;
  const int wg = blockIdx.x;
  const int work = (wg & 7) * 64 + (wg >> 3);
  const int bx = work & 7, by = work >> 3;
  const int brow = by * 128;
  const int bcol = bx * 128;

  const char* Abase = (const char*)A + (size_t)brow * 2048;
  const char* Wb0 = (const char*)W0 + (size_t)bcol * 2048;
  const char* Wb1 = (const char*)W1 + (size_t)bcol * 2048;
  const char* Wb2 = (const char*)W2 + (size_t)bcol * 2048;

  // 6 staging descriptors per thread (4096 granules / 768 threads)
  const char* gsrc[6];
  int gdst[6];
#pragma unroll
  for (int i = 0; i < 6; ++i) {
    int g = tid + i * 768;
    bool val = g < 4096;
    int gg = val ? g : 0;
    int r = (gg & 1023) >> 3;
    int sw = ((gg & 7) * 16) ^ ((r & 7) << 4);
    const char* base;
    if (gg < 1024) base = Abase;
    else {
      int zz = (gg >> 10) - 1;
      base = (zz == 0) ? Wb0 : (zz == 1 ? Wb1 : Wb2);
    }
    gsrc[i] = val ? (base + (size_t)r * 2048 + sw) : nullptr;
    gdst[i] = gg * 16;
  }

  f32x4 acc[4][4];
#pragma unroll
  for (int m = 0; m < 4; ++m)
#pragma unroll
    for (int n = 0; n < 4; ++n) acc[m][n] = (f32x4){0.f, 0.f, 0.f, 0.f};

  // prologue: stage kt=0 into buf0
#pragma unroll
  for (int i = 0; i < 6; ++i)
    if (gsrc[i]) gld16(gsrc[i], sm + gdst[i]);

  for (int kt = 0; kt < 16; ++kt) {
    const int cur = kt & 1, nxt = cur ^ 1;
    if (kt < 15) {
#pragma unroll
      for (int i = 0; i < 6; ++i)
        if (gsrc[i]) gld16(gsrc[i] + (kt + 1) * 128, sm + nxt * 65536 + gdst[i]);
      if (w < 4) asm volatile("s_waitcnt vmcnt(6)" ::: "memory");
      else       asm volatile("s_waitcnt vmcnt(5)" ::: "memory");
    } else {
      asm volatile("s_waitcnt vmcnt(0)" ::: "memory");
    }
    __builtin_amdgcn_sched_barrier(0);
    __builtin_amdgcn_s_barrier();
    __builtin_amdgcn_sched_barrier(0);

    const char* Asw = sm + cur * 65536;
    const char* Bsw = sm + cur * 65536 + 16384 + z * 16384;
#pragma unroll
    for (int kk = 0; kk < 2; ++kk) {
      int kb = kk * 64 + h2 * 16;
      bf16x8 af[4], bfr[4];
#pragma unroll
      for (int m = 0; m < 4; ++m) {
        int r = wm * 64 + m * 16 + l15;
        af[m] = *(const bf16x8*)(Asw + r * 128 + (kb ^ ((r & 7) << 4)));
      }
#pragma unroll
      for (int n = 0; n < 4; ++n) {
        int r = wn * 64 + n * 16 + l15;
        bfr[n] = *(const bf16x8*)(Bsw + r * 128 + (kb ^ ((r & 7) << 4)));
      }
#pragma unroll
      for (int m = 0; m < 4; ++m)
#pragma unroll
        for (int n = 0; n < 4; ++n)
          acc[m][n] = __builtin_amdgcn_mfma_f32_16x16x32_bf16(af[m], bfr[n],
                                                              acc[m][n], 0, 0, 0);
    }
    __builtin_amdgcn_sched_barrier(0);
    __builtin_amdgcn_s_barrier();  // drain-free: next-tile DMAs stay in flight
  }

  const int h = bx * 2 + wn;  // wave spans exactly one head
  if (z == 2) {
    // V transposed: Vh[(b*16+h)*64 + d][s], 8B vector stores along s
#pragma unroll
    for (int m = 0; m < 4; ++m) {
      int row0 = brow + wm * 64 + m * 16 + h2 * 4;
      int b = row0 >> 11, s0 = row0 & 2047;
      size_t base = (size_t)(b * 16 + h) * 64 * 2048 + s0;
#pragma unroll
      for (int n = 0; n < 4; ++n) {
        int dl = n * 16 + l15;
        u16x4 pw;
#pragma unroll
        for (int i = 0; i < 4; ++i) pw[i] = f2bf(acc[m][n][i]);
        *(u16x4*)(Vh + base + (size_t)dl * 2048) = pw;
      }
    }
  } else {
    unsigned short* dst = (z == 0) ? Qh : Kh;
    const float qs = (z == 0) ? 0.18033688f : 1.0f;  // 0.125*log2(e) for Q
#pragma unroll
    for (int m = 0; m < 4; ++m)
#pragma unroll
      for (int i = 0; i < 4; ++i) {
        int row = brow + wm * 64 + m * 16 + h2 * 4 + i;
        int b = row >> 11, s = row & 2047;
        size_t hb2 = ((size_t)(b * 16 + h) * 2048 + s) * 64;
        // RoPE: partner of d (<32) is d+32 = frag n+2, same lane.
#pragma unroll
        for (int n = 0; n < 2; ++n) {
          int dl = n * 16 + l15;
          float c = cosT[s * 64 + dl], sn = sinT[s * 64 + dl];
          float lo = acc[m][n][i], hi = acc[m][n + 2][i];
          dst[hb2 + dl] = f2bf((lo * c - hi * sn) * qs);
          dst[hb2 + dl + 32] = f2bf((hi * c + lo * sn) * qs);
        }
      }
  }
}

// O-proj GEMM v2: double-buffered LDS + counted-vmcnt + XCD swizzle. (Unchanged.)
__global__ __launch_bounds__(256, 2) void gemm_k(
    const unsigned short* __restrict__ A, const unsigned short* __restrict__ W0,
    float* __restrict__ Cout) {
  __shared__ char sm[65536];  // 2 x (A 16KB | B 16KB)
  const int tid = threadIdx.x, lane = tid & 63, w = tid >> 6;
  const int wm = w >> 1, wn = w & 1;
  const int wg = blockIdx.x;
  const int work = (wg & 7) * 64 + (wg >> 3);
  const int bx = work & 7, by = work >> 3;
  const int brow = by * 128;
  const int bcol = bx * 128;

  f32x4 acc[4][4];
#pragma unroll
  for (int m = 0; m < 4; ++m)
#pragma unroll
    for (int n = 0; n < 4; ++n) acc[m][n] = (f32x4){0.f, 0.f, 0.f, 0.f};

  const char* Abase = (const char*)A + (size_t)brow * 2048;
  const char* Bbase = (const char*)W0 + (size_t)bcol * 2048;

  // 8 staging descriptors per thread (4 c-slices x {A,B})
  const char* srcA[4];
  const char* srcB[4];
  int dstO[4];
#pragma unroll
  for (int c = 0; c < 4; ++c) {
    int Lb = w * 4096 + c * 1024;
    int L = Lb + lane * 16;
    int r = L >> 7, kb = L & 127;
    int sw = kb ^ ((r & 7) << 4);
    srcA[c] = Abase + (size_t)r * 2048 + sw;
    srcB[c] = Bbase + (size_t)r * 2048 + sw;
    dstO[c] = Lb;
  }

  // prologue: stage kt=0 into buf0
#pragma unroll
  for (int c = 0; c < 4; ++c) {
    gld16(srcA[c], sm + dstO[c]);
    gld16(srcB[c], sm + 16384 + dstO[c]);
  }

  for (int kt = 0; kt < 16; ++kt) {
    const int cur = kt & 1, nxt = cur ^ 1;
    if (kt < 15) {
#pragma unroll
      for (int c = 0; c < 4; ++c) {
        gld16(srcA[c] + (kt + 1) * 128, sm + nxt * 32768 + dstO[c]);
        gld16(srcB[c] + (kt + 1) * 128, sm + nxt * 32768 + 16384 + dstO[c]);
      }
      asm volatile("s_waitcnt vmcnt(8)" ::: "memory");  // drain this tile only
    } else {
      asm volatile("s_waitcnt vmcnt(0)" ::: "memory");
    }
    __builtin_amdgcn_sched_barrier(0);
    __builtin_amdgcn_s_barrier();
    __builtin_amdgcn_sched_barrier(0);

    const char* As = sm + cur * 32768;
    const char* Bs = sm + cur * 32768 + 16384;
#pragma unroll
    for (int kk = 0; kk < 2; ++kk) {
      int kb = kk * 64 + (lane >> 4) * 16;
      bf16x8 af[4], bfr[4];
#pragma unroll
      for (int m = 0; m < 4; ++m) {
        int r = wm * 64 + m * 16 + (lane & 15);
        af[m] = *(const bf16x8*)(As + r * 128 + (kb ^ ((r & 7) << 4)));
      }
#pragma unroll
      for (int n = 0; n < 4; ++n) {
        int r = wn * 64 + n * 16 + (lane & 15);
        bfr[n] = *(const bf16x8*)(Bs + r * 128 + (kb ^ ((r & 7) << 4)));
      }
#pragma unroll
      for (int m = 0; m < 4; ++m)
#pragma unroll
        for (int n = 0; n < 4; ++n)
          acc[m][n] = __builtin_amdgcn_mfma_f32_16x16x32_bf16(af[m], bfr[n],
                                                              acc[m][n], 0, 0, 0);
    }
    __builtin_amdgcn_sched_barrier(0);
    __builtin_amdgcn_s_barrier();  // drain-free
  }

#pragma unroll
  for (int m = 0; m < 4; ++m)
#pragma unroll
    for (int n = 0; n < 4; ++n)
#pragma unroll
      for (int i = 0; i < 4; ++i) {
        int row = brow + wm * 64 + m * 16 + (lane >> 4) * 4 + i;
        int col = bcol + wn * 64 + n * 16 + (lane & 15);
        Cout[(size_t)row * 1024 + col] = acc[m][n][i];
      }
}

// Flash attention v13: T15 att[2] double-pipeline RETRY at the VGPR-rich
// design point. Identical structure to v12 (QK^T(t+1) MFMA overlaps
// softmax(t) VALU; K staged 2 tiles ahead, V 1; vmcnt 4/2/0 ladder) but
// __launch_bounds__(256,2): VGPR cap 256 hosts the carried 64-reg score
// state without spill (r20's failure was the 128-cap, not the mechanism;
// cf. m214 v36's 249-VGPR config). Occupancy 2 blocks/CU; dual-chain ILP
// substitutes for the lost TLP.
__global__ __launch_bounds__(256, 2) void attn_k(
    const unsigned short* __restrict__ Q, const unsigned short* __restrict__ K,
    const unsigned short* __restrict__ Vt, const float* __restrict__ mask,
    unsigned short* __restrict__ O) {
  __shared__ char Ks[2][8192];
  __shared__ char Vs[2][8192];
  __shared__ float l_arr[4][32];
  const int tid = threadIdx.x, lane = tid & 63, w = tid >> 6;
  const int q31 = lane & 31, hi = lane >> 5;
  const int wg = blockIdx.x;
  const int work = (wg & 7) * 128 + (wg >> 3);
  const int qt = work & 15, hl = work >> 4;
  const int h = hl & 15, b = hl >> 4;
  const size_t hb = (size_t)(b * 16 + h) * (2048 * 64);
  const int q0 = qt * 128 + w * 32;
  const float L2E = 1.44269504f;
  const float MREF = 12.0f;
  const int rdo = q31 * 32 + hi * 16;  // lane offset within any 1KB block

  bf16x8 qb[4];
  {
    const char* qrow = (const char*)(Q + hb + (size_t)(q0 + q31) * 64);
#pragma unroll
    for (int ks = 0; ks < 4; ++ks)
      qb[ks] = *(const bf16x8*)(qrow + ks * 32 + hi * 16);
  }

  float l_part = 0.f;
  f32x16 oacc[2];
#pragma unroll
  for (int e = 0; e < 16; ++e) { oacc[0][e] = 0.f; oacc[1][e] = 0.f; }

  int koff0, koff1, vof0, vof1;
  {
    int L0 = w * 2048 + lane * 16;
    int c0 = L0 >> 12, ks0 = (L0 >> 10) & 3, q0l = (L0 >> 5) & 31,
        hi0 = (L0 >> 4) & 1;
    int row0 = c0 * 32 + q0l, kb0 = ks0 * 32 + hi0 * 16;
    koff0 = row0 * 128 + kb0;
    vof0 = row0 * 4096 + kb0;
    int L1 = L0 + 1024;
    int c1 = L1 >> 12, ks1 = (L1 >> 10) & 3, q1l = (L1 >> 5) & 31,
        hi1 = (L1 >> 4) & 1;
    int row1 = c1 * 32 + q1l, kb1 = ks1 * 32 + hi1 * 16;
    koff1 = row1 * 128 + kb1;
    vof1 = row1 * 4096 + kb1;
  }
  const char* Kg = (const char*)(K + hb);
  const char* Vg = (const char*)(Vt + hb);
  const float* mp = mask + (size_t)b * 2048;

  // QK^T for one 32-kv c-tile (C-init = mask*log2e - MREF)
  auto qkc = [&](const char* ksb, const float* mrow, int c) -> f32x16 {
    f32x16 s;
#pragma unroll
    for (int g = 0; g < 4; ++g) {
      f32x4 mv = *(const f32x4*)(mrow + c * 32 + g * 8 + hi * 4);
#pragma unroll
      for (int i = 0; i < 4; ++i) s[g * 4 + i] = fmaf(mv[i], L2E, -MREF);
    }
    __builtin_amdgcn_s_setprio(1);
#pragma unroll
    for (int ks = 0; ks < 4; ++ks) {
      bf16x8 kf = *(const bf16x8*)(ksb + (c * 4 + ks) * 1024 + rdo);
      s = __builtin_amdgcn_mfma_f32_32x32x16_bf16(kf, qb[ks], s, 0, 0, 0);
    }
    __builtin_amdgcn_s_setprio(0);
    return s;
  };

  // exp2 + per-lane partial sum + pack C-layout -> two A-frag dword pairs
  auto smpack = [&](f32x16& s, pu4& pa, pu4& pb) {
#pragma unroll
    for (int e = 0; e < 16; ++e) s[e] = __builtin_amdgcn_exp2f(s[e]);
    l_part += ((s[0] + s[1]) + (s[2] + s[3])) + ((s[4] + s[5]) + (s[6] + s[7])) +
              ((s[8] + s[9]) + (s[10] + s[11])) +
              ((s[12] + s[13]) + (s[14] + s[15]));
#pragma unroll
    for (int par = 0; par < 2; ++par) {
      unsigned a0 = cvtpk(s[par * 8 + 0], s[par * 8 + 1]);
      unsigned a1 = cvtpk(s[par * 8 + 2], s[par * 8 + 3]);
      unsigned b0 = cvtpk(s[par * 8 + 4], s[par * 8 + 5]);
      unsigned b1 = cvtpk(s[par * 8 + 6], s[par * 8 + 7]);
      asm("v_permlane32_swap_b32 %0, %1" : "+v"(a0), "+v"(b0));
      asm("v_permlane32_swap_b32 %0, %1" : "+v"(a1), "+v"(b1));
      pu4& pp = par ? pb : pa;
      pp.u[0] = a0; pp.u[1] = a1; pp.u[2] = b0; pp.u[3] = b1;
    }
  };

  // ---- prologue: stage K0,V0,K1; QK^T(0) ----
  gld16(Kg + koff0, Ks[0] + w * 2048);
  gld16(Kg + koff1, Ks[0] + w * 2048 + 1024);
  gld16(Vg + vof0, Vs[0] + w * 2048);
  gld16(Vg + vof1, Vs[0] + w * 2048 + 1024);
  gld16(Kg + 8192 + koff0, Ks[1] + w * 2048);
  gld16(Kg + 8192 + koff1, Ks[1] + w * 2048 + 1024);
  asm volatile("s_waitcnt vmcnt(2)" ::: "memory");  // drain K0,V0; K1 in flight
  __builtin_amdgcn_sched_barrier(0);
  __builtin_amdgcn_s_barrier();
  __builtin_amdgcn_sched_barrier(0);

  f32x16 sA0, sA1, sB0, sB1;
  sA0 = qkc(Ks[0], mp, 0);
  sA1 = qkc(Ks[0], mp, 1);
  __builtin_amdgcn_sched_barrier(0);
  __builtin_amdgcn_s_barrier();  // protect Ks[0] from body-0's K(2) write

  auto body = [&](auto vbc, int t, f32x16& sP0, f32x16& sP1, f32x16& sN0,
                  f32x16& sN1) {
    constexpr int vb = decltype(vbc)::v;  // Vs buffer for PV(t) = t&1
    constexpr int kb1 = 1 - vb;           // Ks buffer for QK^T(t+1)
    if (t < 30) {
      const char* kp = Kg + (size_t)(t + 2) * 8192;
      gld16(kp + koff0, Ks[vb] + w * 2048);
      gld16(kp + koff1, Ks[vb] + w * 2048 + 1024);
    }
    if (t < 31) {
      const char* vp = Vg + (size_t)(t + 1) * 128;
      gld16(vp + vof0, Vs[kb1] + w * 2048);
      gld16(vp + vof1, Vs[kb1] + w * 2048 + 1024);
    }
    if (t < 30) asm volatile("s_waitcnt vmcnt(4)" ::: "memory");
    else if (t < 31) asm volatile("s_waitcnt vmcnt(2)" ::: "memory");
    else asm volatile("s_waitcnt vmcnt(0)" ::: "memory");
    __builtin_amdgcn_sched_barrier(0);
    __builtin_amdgcn_s_barrier();
    __builtin_amdgcn_sched_barrier(0);

    const float* mnext = mp + (t + 1) * 64;
    pu4 p0, p1, p2, p3;
    // QK^T(t+1) MFMAs overlap softmax(t) VALU (independent chains)
    if (t < 31) sN0 = qkc(Ks[kb1], mnext, 0);
    smpack(sP0, p0, p1);
    if (t < 31) sN1 = qkc(Ks[kb1], mnext, 1);
    smpack(sP1, p2, p3);

    // ---- PV(t) ----
    __builtin_amdgcn_s_setprio(1);
#pragma unroll
    for (int t2 = 0; t2 < 4; ++t2) {
      const pu4& pp = (t2 == 0) ? p0 : (t2 == 1) ? p1 : (t2 == 2) ? p2 : p3;
      union { unsigned u[4]; bf16x8 v; } puv;
      puv.u[0] = pp.u[0]; puv.u[1] = pp.u[1];
      puv.u[2] = pp.u[2]; puv.u[3] = pp.u[3];
      bf16x8 vf0 = *(const bf16x8*)(Vs[vb] + t2 * 1024 + rdo);
      bf16x8 vf1 = *(const bf16x8*)(Vs[vb] + 4096 + t2 * 1024 + rdo);
      oacc[0] = __builtin_amdgcn_mfma_f32_32x32x16_bf16(puv.v, vf0, oacc[0],
                                                        0, 0, 0);
      oacc[1] = __builtin_amdgcn_mfma_f32_32x32x16_bf16(puv.v, vf1, oacc[1],
                                                        0, 0, 0);
    }
    __builtin_amdgcn_s_setprio(0);
    __builtin_amdgcn_sched_barrier(0);
    __builtin_amdgcn_s_barrier();  // drain-free
  };

  for (int t = 0; t < 32; t += 2) {
    body(ic<0>{}, t, sA0, sA1, sB0, sB1);
    body(ic<1>{}, t + 1, sB0, sB1, sA0, sA1);
  }

  float lr = l_part + __shfl_xor(l_part, 32, 64);
  l_arr[w][q31] = 1.0f / lr;  // both hi-halves write the same value

#pragma unroll
  for (int g = 0; g < 4; ++g) {
    f32x4 iv = *(const f32x4*)(&l_arr[w][g * 8 + hi * 4]);
    const int qrow = q0 + g * 8 + hi * 4;
#pragma unroll
    for (int i = 0; i < 4; ++i) {
      size_t rb = (size_t)(b * 2048 + qrow + i) * 1024 + h * 64;
      O[rb + q31] = f2bfn(oacc[0][g * 4 + i] * iv[i]);
      O[rb + 32 + q31] = f2bfn(oacc[1][g * 4 + i] * iv[i]);
    }
  }
}

extern "C" void kernel_launch(void* const* d_in, const int* in_sizes, int n_in,
                              void* d_out, int out_size, void* d_ws, size_t ws_size,
                              hipStream_t stream) {
  const float* hidden = (const float*)d_in[0];
  const float* amask = (const float*)d_in[1];
  const float* cosT = (const float*)d_in[2];
  const float* sinT = (const float*)d_in[3];
  const float* Wq = (const float*)d_in[4];
  const float* Wk = (const float*)d_in[5];
  const float* Wv = (const float*)d_in[6];
  const float* Wo = (const float*)d_in[7];
  float* out = (float*)d_out;

  // ws layout (bf16): Xb 8M | Wq,Wk,Wv,Wo 1M each | Qh,Kh,Vt,Ob 8M each = 88 MB
  if (ws_size < (size_t)92274688) return;
  unsigned short* Xb = (unsigned short*)d_ws;
  unsigned short* Wqb = Xb + (size_t)8192 * 1024;
  unsigned short* Wkb = Wqb + (size_t)1024 * 1024;
  unsigned short* Wvb = Wkb + (size_t)1024 * 1024;
  unsigned short* Wob = Wvb + (size_t)1024 * 1024;
  unsigned short* Qh = Wob + (size_t)1024 * 1024;
  unsigned short* Kh = Qh + (size_t)8388608;
  unsigned short* Vt = Kh + (size_t)8388608;
  unsigned short* Ob = Vt + (size_t)8388608;

  cvt_all<<<6144, 256, 0, stream>>>(hidden, Wq, Wk, Wv, Wo, Xb, Wqb);

  gemm_qkv<<<512, 768, 0, stream>>>(Xb, Wqb, Wkb, Wvb, cosT, sinT, Qh, Kh, Vt);
  attn_k<<<1024, 256, 0, stream>>>(Qh, Kh, Vt, amask, Ob);
  gemm_k<<<512, 256, 0, stream>>>(Ob, Wob, out);
}

// Round 23
// 191.560 us; speedup vs baseline: 1.1030x; 1.1030x over previous
//
#include <hip/hip_runtime.h>

// ModernBertAttention fused pipeline, bf16 MFMA, fp32 I/O.
// B=4 S=2048 H=1024 NH=16 D=64.
// Session-optimal composition (rounds 19/21, 191.3-191.8 us measured):
//   cvt_all    (12 us, HBM-bound)
//   gemm_qkv   (48 us: fused QKV, 12-wave, dbuf + counted-vmcnt + XCD swizzle)
//   attn_k v11 (99 us: 32x32 MFMA, in-reg P transpose, fixed-ref softmax,
//               block-granule LDS, counted-vmcnt, XCD swizzle)
//   gemm_k     (21 us: dbuf + counted-vmcnt + XCD swizzle)

typedef __bf16 bf16x8 __attribute__((ext_vector_type(8)));
typedef float f32x4 __attribute__((ext_vector_type(4)));
typedef float f32x16 __attribute__((ext_vector_type(16)));
typedef unsigned short u16x8 __attribute__((ext_vector_type(8)));
typedef unsigned short u16x4 __attribute__((ext_vector_type(4)));
typedef const __attribute__((address_space(1))) void* gptr_t;
typedef __attribute__((address_space(3))) void* lptr_t;

template <int N> struct ic { static constexpr int v = N; };

__device__ __forceinline__ unsigned short f2bf(float f) {
  union { float f; unsigned u; } v; v.f = f;
  unsigned r = (v.u + 0x7fffu + ((v.u >> 16) & 1u)) >> 16;  // RNE
  return (unsigned short)r;
}

__device__ __forceinline__ unsigned short f2bfn(float f) {
  union { __bf16 h; unsigned short u; } v;
  v.h = (__bf16)f;  // native v_cvt
  return v.u;
}

__device__ __forceinline__ unsigned cvtpk(float lo, float hi_) {
  unsigned r;
  asm("v_cvt_pk_bf16_f32 %0, %1, %2" : "=v"(r) : "v"(lo), "v"(hi_));
  return r;
}

__device__ __forceinline__ void gld16(const void* g, void* l) {
  __builtin_amdgcn_global_load_lds((gptr_t)g, (lptr_t)l, 16, 0, 0);
}

// fused f32->bf16 for hidden (8M elems) + 4 weights (4x1M elems, contiguous dst)
__global__ __launch_bounds__(256) void cvt_all(
    const float* __restrict__ hidden, const float* __restrict__ Wq,
    const float* __restrict__ Wk, const float* __restrict__ Wv,
    const float* __restrict__ Wo, unsigned short* __restrict__ Xb,
    unsigned short* __restrict__ Wb) {
  size_t i8 = ((size_t)blockIdx.x * 256 + threadIdx.x) * 8;
  const float* src;
  unsigned short* dst;
  if (i8 < 8388608) {
    src = hidden + i8;
    dst = Xb + i8;
  } else {
    size_t r = i8 - 8388608;
    int wsel = (int)(r >> 20);
    size_t off = r & 1048575;
    const float* wsrc = (wsel == 0) ? Wq : (wsel == 1) ? Wk : (wsel == 2) ? Wv : Wo;
    src = wsrc + off;
    dst = Wb + r;
  }
  f32x4 a = *(const f32x4*)(src);
  f32x4 b = *(const f32x4*)(src + 4);
  u16x8 o;
  o[0] = f2bf(a[0]); o[1] = f2bf(a[1]); o[2] = f2bf(a[2]); o[3] = f2bf(a[3]);
  o[4] = f2bf(b[0]); o[5] = f2bf(b[1]); o[6] = f2bf(b[2]); o[7] = f2bf(b[3]);
  *(u16x8*)dst = o;
}

// Fused QKV GEMM v2: 128x128 C-tile for all three weights; 12 waves;
// double-buffered LDS + counted-vmcnt pipeline + XCD swizzle.
__global__ __launch_bounds__(768, 3) void gemm_qkv(
    const unsigned short* __restrict__ A,
    const unsigned short* __restrict__ W0, const unsigned short* __restrict__ W1,
    const unsigned short* __restrict__ W2,
    const float* __restrict__ cosT, const float* __restrict__ sinT,
    unsigned short* __restrict__ Qh, unsigned short* __restrict__ Kh,
    unsigned short* __restrict__ Vh) {
  __shared__ char sm[131072];  // 2 x (A | W0 | W1 | W2), 16KB each
  const int tid = threadIdx.x, lane = tid & 63, w = tid >> 6;
  const int l15 = lane & 15, h2 = lane >> 4;
  const int z = w >> 2, sub = w & 3;
  const int wm = sub >> 1, wn = sub & 1;
  const int wg = blockIdx.x;
  const int work = (wg & 7) * 64 + (wg >> 3);
  const int bx = work & 7, by = work >> 3;
  const int brow = by * 128;
  const int bcol = bx * 128;

  const char* Abase = (const char*)A + (size_t)brow * 2048;
  const char* Wb0 = (const char*)W0 + (size_t)bcol * 2048;
  const char* Wb1 = (const char*)W1 + (size_t)bcol * 2048;
  const char* Wb2 = (const char*)W2 + (size_t)bcol * 2048;

  // 6 staging descriptors per thread (4096 granules / 768 threads)
  const char* gsrc[6];
  int gdst[6];
#pragma unroll
  for (int i = 0; i < 6; ++i) {
    int g = tid + i * 768;
    bool val = g < 4096;
    int gg = val ? g : 0;
    int r = (gg & 1023) >> 3;
    int sw = ((gg & 7) * 16) ^ ((r & 7) << 4);
    const char* base;
    if (gg < 1024) base = Abase;
    else {
      int zz = (gg >> 10) - 1;
      base = (zz == 0) ? Wb0 : (zz == 1 ? Wb1 : Wb2);
    }
    gsrc[i] = val ? (base + (size_t)r * 2048 + sw) : nullptr;
    gdst[i] = gg * 16;
  }

  f32x4 acc[4][4];
#pragma unroll
  for (int m = 0; m < 4; ++m)
#pragma unroll
    for (int n = 0; n < 4; ++n) acc[m][n] = (f32x4){0.f, 0.f, 0.f, 0.f};

  // prologue: stage kt=0 into buf0
#pragma unroll
  for (int i = 0; i < 6; ++i)
    if (gsrc[i]) gld16(gsrc[i], sm + gdst[i]);

  for (int kt = 0; kt < 16; ++kt) {
    const int cur = kt & 1, nxt = cur ^ 1;
    if (kt < 15) {
#pragma unroll
      for (int i = 0; i < 6; ++i)
        if (gsrc[i]) gld16(gsrc[i] + (kt + 1) * 128, sm + nxt * 65536 + gdst[i]);
      if (w < 4) asm volatile("s_waitcnt vmcnt(6)" ::: "memory");
      else       asm volatile("s_waitcnt vmcnt(5)" ::: "memory");
    } else {
      asm volatile("s_waitcnt vmcnt(0)" ::: "memory");
    }
    __builtin_amdgcn_sched_barrier(0);
    __builtin_amdgcn_s_barrier();
    __builtin_amdgcn_sched_barrier(0);

    const char* Asw = sm + cur * 65536;
    const char* Bsw = sm + cur * 65536 + 16384 + z * 16384;
#pragma unroll
    for (int kk = 0; kk < 2; ++kk) {
      int kb = kk * 64 + h2 * 16;
      bf16x8 af[4], bfr[4];
#pragma unroll
      for (int m = 0; m < 4; ++m) {
        int r = wm * 64 + m * 16 + l15;
        af[m] = *(const bf16x8*)(Asw + r * 128 + (kb ^ ((r & 7) << 4)));
      }
#pragma unroll
      for (int n = 0; n < 4; ++n) {
        int r = wn * 64 + n * 16 + l15;
        bfr[n] = *(const bf16x8*)(Bsw + r * 128 + (kb ^ ((r & 7) << 4)));
      }
#pragma unroll
      for (int m = 0; m < 4; ++m)
#pragma unroll
        for (int n = 0; n < 4; ++n)
          acc[m][n] = __builtin_amdgcn_mfma_f32_16x16x32_bf16(af[m], bfr[n],
                                                              acc[m][n], 0, 0, 0);
    }
    __builtin_amdgcn_sched_barrier(0);
    __builtin_amdgcn_s_barrier();  // drain-free: next-tile DMAs stay in flight
  }

  const int h = bx * 2 + wn;  // wave spans exactly one head
  if (z == 2) {
    // V transposed: Vh[(b*16+h)*64 + d][s], 8B vector stores along s
#pragma unroll
    for (int m = 0; m < 4; ++m) {
      int row0 = brow + wm * 64 + m * 16 + h2 * 4;
      int b = row0 >> 11, s0 = row0 & 2047;
      size_t base = (size_t)(b * 16 + h) * 64 * 2048 + s0;
#pragma unroll
      for (int n = 0; n < 4; ++n) {
        int dl = n * 16 + l15;
        u16x4 pw;
#pragma unroll
        for (int i = 0; i < 4; ++i) pw[i] = f2bf(acc[m][n][i]);
        *(u16x4*)(Vh + base + (size_t)dl * 2048) = pw;
      }
    }
  } else {
    unsigned short* dst = (z == 0) ? Qh : Kh;
    const float qs = (z == 0) ? 0.18033688f : 1.0f;  // 0.125*log2(e) for Q
#pragma unroll
    for (int m = 0; m < 4; ++m)
#pragma unroll
      for (int i = 0; i < 4; ++i) {
        int row = brow + wm * 64 + m * 16 + h2 * 4 + i;
        int b = row >> 11, s = row & 2047;
        size_t hb2 = ((size_t)(b * 16 + h) * 2048 + s) * 64;
        // RoPE: partner of d (<32) is d+32 = frag n+2, same lane.
#pragma unroll
        for (int n = 0; n < 2; ++n) {
          int dl = n * 16 + l15;
          float c = cosT[s * 64 + dl], sn = sinT[s * 64 + dl];
          float lo = acc[m][n][i], hi = acc[m][n + 2][i];
          dst[hb2 + dl] = f2bf((lo * c - hi * sn) * qs);
          dst[hb2 + dl + 32] = f2bf((hi * c + lo * sn) * qs);
        }
      }
  }
}

// O-proj GEMM v2: double-buffered LDS + counted-vmcnt + XCD swizzle.
__global__ __launch_bounds__(256, 2) void gemm_k(
    const unsigned short* __restrict__ A, const unsigned short* __restrict__ W0,
    float* __restrict__ Cout) {
  __shared__ char sm[65536];  // 2 x (A 16KB | B 16KB)
  const int tid = threadIdx.x, lane = tid & 63, w = tid >> 6;
  const int wm = w >> 1, wn = w & 1;
  const int wg = blockIdx.x;
  const int work = (wg & 7) * 64 + (wg >> 3);
  const int bx = work & 7, by = work >> 3;
  const int brow = by * 128;
  const int bcol = bx * 128;

  f32x4 acc[4][4];
#pragma unroll
  for (int m = 0; m < 4; ++m)
#pragma unroll
    for (int n = 0; n < 4; ++n) acc[m][n] = (f32x4){0.f, 0.f, 0.f, 0.f};

  const char* Abase = (const char*)A + (size_t)brow * 2048;
  const char* Bbase = (const char*)W0 + (size_t)bcol * 2048;

  // 8 staging descriptors per thread (4 c-slices x {A,B})
  const char* srcA[4];
  const char* srcB[4];
  int dstO[4];
#pragma unroll
  for (int c = 0; c < 4; ++c) {
    int Lb = w * 4096 + c * 1024;
    int L = Lb + lane * 16;
    int r = L >> 7, kb = L & 127;
    int sw = kb ^ ((r & 7) << 4);
    srcA[c] = Abase + (size_t)r * 2048 + sw;
    srcB[c] = Bbase + (size_t)r * 2048 + sw;
    dstO[c] = Lb;
  }

  // prologue: stage kt=0 into buf0
#pragma unroll
  for (int c = 0; c < 4; ++c) {
    gld16(srcA[c], sm + dstO[c]);
    gld16(srcB[c], sm + 16384 + dstO[c]);
  }

  for (int kt = 0; kt < 16; ++kt) {
    const int cur = kt & 1, nxt = cur ^ 1;
    if (kt < 15) {
#pragma unroll
      for (int c = 0; c < 4; ++c) {
        gld16(srcA[c] + (kt + 1) * 128, sm + nxt * 32768 + dstO[c]);
        gld16(srcB[c] + (kt + 1) * 128, sm + nxt * 32768 + 16384 + dstO[c]);
      }
      asm volatile("s_waitcnt vmcnt(8)" ::: "memory");  // drain this tile only
    } else {
      asm volatile("s_waitcnt vmcnt(0)" ::: "memory");
    }
    __builtin_amdgcn_sched_barrier(0);
    __builtin_amdgcn_s_barrier();
    __builtin_amdgcn_sched_barrier(0);

    const char* As = sm + cur * 32768;
    const char* Bs = sm + cur * 32768 + 16384;
#pragma unroll
    for (int kk = 0; kk < 2; ++kk) {
      int kb = kk * 64 + (lane >> 4) * 16;
      bf16x8 af[4], bfr[4];
#pragma unroll
      for (int m = 0; m < 4; ++m) {
        int r = wm * 64 + m * 16 + (lane & 15);
        af[m] = *(const bf16x8*)(As + r * 128 + (kb ^ ((r & 7) << 4)));
      }
#pragma unroll
      for (int n = 0; n < 4; ++n) {
        int r = wn * 64 + n * 16 + (lane & 15);
        bfr[n] = *(const bf16x8*)(Bs + r * 128 + (kb ^ ((r & 7) << 4)));
      }
#pragma unroll
      for (int m = 0; m < 4; ++m)
#pragma unroll
        for (int n = 0; n < 4; ++n)
          acc[m][n] = __builtin_amdgcn_mfma_f32_16x16x32_bf16(af[m], bfr[n],
                                                              acc[m][n], 0, 0, 0);
    }
    __builtin_amdgcn_sched_barrier(0);
    __builtin_amdgcn_s_barrier();  // drain-free
  }

#pragma unroll
  for (int m = 0; m < 4; ++m)
#pragma unroll
    for (int n = 0; n < 4; ++n)
#pragma unroll
      for (int i = 0; i < 4; ++i) {
        int row = brow + wm * 64 + m * 16 + (lane >> 4) * 4 + i;
        int col = bcol + wn * 64 + n * 16 + (lane & 15);
        Cout[(size_t)row * 1024 + col] = acc[m][n][i];
      }
}

// Flash attention v11 (session-best, 99.3 us): 32x32x16 MFMA, in-register P
// transpose (cvt_pk + permlane32_swap), fixed-reference softmax (exp2,
// MREF=12), block-granule LDS, counted-vmcnt pipeline, XCD swizzle.
// T15 2-deep score pipelining rejected: spills at 128-VGPR cap (r20),
// occupancy-dominated at 256-cap (r22: 124 us, 8 waves/CU).
__global__ __launch_bounds__(256, 4) void attn_k(
    const unsigned short* __restrict__ Q, const unsigned short* __restrict__ K,
    const unsigned short* __restrict__ Vt, const float* __restrict__ mask,
    unsigned short* __restrict__ O) {
  __shared__ char Ks[2][8192];
  __shared__ char Vs[2][8192];
  __shared__ float l_arr[4][32];
  const int tid = threadIdx.x, lane = tid & 63, w = tid >> 6;
  const int q31 = lane & 31, hi = lane >> 5;
  const int wg = blockIdx.x;
  const int work = (wg & 7) * 128 + (wg >> 3);
  const int qt = work & 15, hl = work >> 4;
  const int h = hl & 15, b = hl >> 4;
  const size_t hb = (size_t)(b * 16 + h) * (2048 * 64);
  const int q0 = qt * 128 + w * 32;
  const float L2E = 1.44269504f;
  const float MREF = 12.0f;
  const int rdo = q31 * 32 + hi * 16;  // lane offset within any 1KB block

  bf16x8 qb[4];
  {
    const char* qrow = (const char*)(Q + hb + (size_t)(q0 + q31) * 64);
#pragma unroll
    for (int ks = 0; ks < 4; ++ks)
      qb[ks] = *(const bf16x8*)(qrow + ks * 32 + hi * 16);
  }

  float l_part = 0.f;
  f32x16 oacc[2];
#pragma unroll
  for (int e = 0; e < 16; ++e) { oacc[0][e] = 0.f; oacc[1][e] = 0.f; }

  int koff0, koff1, vof0, vof1;
  {
    int L0 = w * 2048 + lane * 16;
    int c0 = L0 >> 12, ks0 = (L0 >> 10) & 3, q0l = (L0 >> 5) & 31,
        hi0 = (L0 >> 4) & 1;
    int row0 = c0 * 32 + q0l, kb0 = ks0 * 32 + hi0 * 16;
    koff0 = row0 * 128 + kb0;
    vof0 = row0 * 4096 + kb0;
    int L1 = L0 + 1024;
    int c1 = L1 >> 12, ks1 = (L1 >> 10) & 3, q1l = (L1 >> 5) & 31,
        hi1 = (L1 >> 4) & 1;
    int row1 = c1 * 32 + q1l, kb1 = ks1 * 32 + hi1 * 16;
    koff1 = row1 * 128 + kb1;
    vof1 = row1 * 4096 + kb1;
  }
  const char* Kg = (const char*)(K + hb);
  const char* Vg = (const char*)(Vt + hb);
  const float* mp = mask + (size_t)b * 2048;

  gld16(Kg + koff0, Ks[0] + w * 2048);
  gld16(Kg + koff1, Ks[0] + w * 2048 + 1024);
  gld16(Vg + vof0, Vs[0] + w * 2048);
  gld16(Vg + vof1, Vs[0] + w * 2048 + 1024);

  auto body = [&](auto curc, int t) {
    constexpr int cur = decltype(curc)::v;
    constexpr int nxt = 1 - cur;
    if (t < 31) {
      const char* kp = Kg + (size_t)(t + 1) * 8192;
      const char* vp = Vg + (size_t)(t + 1) * 128;
      gld16(kp + koff0, Ks[nxt] + w * 2048);
      gld16(kp + koff1, Ks[nxt] + w * 2048 + 1024);
      gld16(vp + vof0, Vs[nxt] + w * 2048);
      gld16(vp + vof1, Vs[nxt] + w * 2048 + 1024);
      asm volatile("s_waitcnt vmcnt(4)" ::: "memory");  // drain tile-t only
    } else {
      asm volatile("s_waitcnt vmcnt(0)" ::: "memory");  // tail: drain all
    }
    __builtin_amdgcn_sched_barrier(0);
    __builtin_amdgcn_s_barrier();
    __builtin_amdgcn_sched_barrier(0);

    const float* mrow = mp + t * 64;

    f32x16 sacc[2];
#pragma unroll
    for (int c = 0; c < 2; ++c) {
#pragma unroll
      for (int g = 0; g < 4; ++g) {
        f32x4 mv = *(const f32x4*)(mrow + c * 32 + g * 8 + hi * 4);
#pragma unroll
        for (int i = 0; i < 4; ++i)
          sacc[c][g * 4 + i] = fmaf(mv[i], L2E, -MREF);
      }
      __builtin_amdgcn_s_setprio(1);
#pragma unroll
      for (int ks = 0; ks < 4; ++ks) {
        bf16x8 kf =
            *(const bf16x8*)(Ks[cur] + (c * 4 + ks) * 1024 + rdo);
        sacc[c] = __builtin_amdgcn_mfma_f32_32x32x16_bf16(kf, qb[ks], sacc[c],
                                                          0, 0, 0);
      }
      __builtin_amdgcn_s_setprio(0);
#pragma unroll
      for (int e = 0; e < 16; ++e)
        sacc[c][e] = __builtin_amdgcn_exp2f(sacc[c][e]);
      float s0 = (sacc[c][0] + sacc[c][1]) + (sacc[c][2] + sacc[c][3]);
      float s1 = (sacc[c][4] + sacc[c][5]) + (sacc[c][6] + sacc[c][7]);
      float s2 = (sacc[c][8] + sacc[c][9]) + (sacc[c][10] + sacc[c][11]);
      float s3 = (sacc[c][12] + sacc[c][13]) + (sacc[c][14] + sacc[c][15]);
      l_part += (s0 + s1) + (s2 + s3);
    }

    __builtin_amdgcn_s_setprio(1);
#pragma unroll
    for (int c = 0; c < 2; ++c) {
#pragma unroll
      for (int par = 0; par < 2; ++par) {
        const int t2 = c * 2 + par;
        unsigned a0 = cvtpk(sacc[c][par * 8 + 0], sacc[c][par * 8 + 1]);
        unsigned a1 = cvtpk(sacc[c][par * 8 + 2], sacc[c][par * 8 + 3]);
        unsigned b0 = cvtpk(sacc[c][par * 8 + 4], sacc[c][par * 8 + 5]);
        unsigned b1 = cvtpk(sacc[c][par * 8 + 6], sacc[c][par * 8 + 7]);
        asm("v_permlane32_swap_b32 %0, %1" : "+v"(a0), "+v"(b0));
        asm("v_permlane32_swap_b32 %0, %1" : "+v"(a1), "+v"(b1));
        union { unsigned u[4]; bf16x8 v; } pu;
        pu.u[0] = a0; pu.u[1] = a1; pu.u[2] = b0; pu.u[3] = b1;
        bf16x8 vf0 = *(const bf16x8*)(Vs[cur] + t2 * 1024 + rdo);
        bf16x8 vf1 = *(const bf16x8*)(Vs[cur] + 4096 + t2 * 1024 + rdo);
        oacc[0] = __builtin_amdgcn_mfma_f32_32x32x16_bf16(pu.v, vf0, oacc[0],
                                                          0, 0, 0);
        oacc[1] = __builtin_amdgcn_mfma_f32_32x32x16_bf16(pu.v, vf1, oacc[1],
                                                          0, 0, 0);
      }
    }
    __builtin_amdgcn_s_setprio(0);
    __builtin_amdgcn_sched_barrier(0);
    __builtin_amdgcn_s_barrier();  // drain-free: tile-t+2 loads stay in flight
  };

  for (int t = 0; t < 32; t += 2) {
    body(ic<0>{}, t);
    body(ic<1>{}, t + 1);
  }

  float lr = l_part + __shfl_xor(l_part, 32, 64);
  l_arr[w][q31] = 1.0f / lr;  // both hi-halves write the same value

#pragma unroll
  for (int g = 0; g < 4; ++g) {
    f32x4 iv = *(const f32x4*)(&l_arr[w][g * 8 + hi * 4]);
    const int qrow = q0 + g * 8 + hi * 4;
#pragma unroll
    for (int i = 0; i < 4; ++i) {
      size_t rb = (size_t)(b * 2048 + qrow + i) * 1024 + h * 64;
      O[rb + q31] = f2bfn(oacc[0][g * 4 + i] * iv[i]);
      O[rb + 32 + q31] = f2bfn(oacc[1][g * 4 + i] * iv[i]);
    }
  }
}

extern "C" void kernel_launch(void* const* d_in, const int* in_sizes, int n_in,
                              void* d_out, int out_size, void* d_ws, size_t ws_size,
                              hipStream_t stream) {
  const float* hidden = (const float*)d_in[0];
  const float* amask = (const float*)d_in[1];
  const float* cosT = (const float*)d_in[2];
  const float* sinT = (const float*)d_in[3];
  const float* Wq = (const float*)d_in[4];
  const float* Wk = (const float*)d_in[5];
  const float* Wv = (const float*)d_in[6];
  const float* Wo = (const float*)d_in[7];
  float* out = (float*)d_out;

  // ws layout (bf16): Xb 8M | Wq,Wk,Wv,Wo 1M each | Qh,Kh,Vt,Ob 8M each = 88 MB
  if (ws_size < (size_t)92274688) return;
  unsigned short* Xb = (unsigned short*)d_ws;
  unsigned short* Wqb = Xb + (size_t)8192 * 1024;
  unsigned short* Wkb = Wqb + (size_t)1024 * 1024;
  unsigned short* Wvb = Wkb + (size_t)1024 * 1024;
  unsigned short* Wob = Wvb + (size_t)1024 * 1024;
  unsigned short* Qh = Wob + (size_t)1024 * 1024;
  unsigned short* Kh = Qh + (size_t)8388608;
  unsigned short* Vt = Kh + (size_t)8388608;
  unsigned short* Ob = Vt + (size_t)8388608;

  cvt_all<<<6144, 256, 0, stream>>>(hidden, Wq, Wk, Wv, Wo, Xb, Wqb);

  gemm_qkv<<<512, 768, 0, stream>>>(Xb, Wqb, Wkb, Wvb, cosT, sinT, Qh, Kh, Vt);
  attn_k<<<1024, 256, 0, stream>>>(Qh, Kh, Vt, amask, Ob);
  gemm_k<<<512, 256, 0, stream>>>(Ob, Wob, out);
}